// Round 1
// baseline (319.827 us; speedup 1.0000x reference)
//
#include <hip/hip_runtime.h>

#define B_ROWS 16384
#define FEAT   2048
#define MARGIN 1.0f
#define RPB    4                    // rows per block == waves per block
#define NBLK   (B_ROWS / RPB)       // 4096 stage-1 blocks / ws partials

typedef float vfloat4 __attribute__((ext_vector_type(4)));

// Stage 1: one WAVE per row. 2048 floats/row / 64 lanes = 32 floats =
// 8 float4 per lane per stream -> 24 independent 1-KB wave-loads in flight.
// No cross-wave reduction for the row sums (wave-internal butterfly only);
// one tiny LDS step folds the 4 row-losses into a single per-block partial.
__global__ __launch_bounds__(256) void TripletLoss_90091234001212_kernel(
    const float* __restrict__ anc,
    const float* __restrict__ pos,
    const float* __restrict__ neg,
    float* __restrict__ ws)
{
    const int tid  = threadIdx.x;
    const int lane = tid & 63;
    const int wave = tid >> 6;
    const int row  = blockIdx.x * RPB + wave;

    const vfloat4* a4 = (const vfloat4*)(anc + (size_t)row * FEAT);
    const vfloat4* p4 = (const vfloat4*)(pos + (size_t)row * FEAT);
    const vfloat4* n4 = (const vfloat4*)(neg + (size_t)row * FEAT);

    vfloat4 a[8], p[8], n[8];
    #pragma unroll
    for (int k = 0; k < 8; ++k) a[k] = __builtin_nontemporal_load(&a4[lane + 64 * k]);
    #pragma unroll
    for (int k = 0; k < 8; ++k) p[k] = __builtin_nontemporal_load(&p4[lane + 64 * k]);
    #pragma unroll
    for (int k = 0; k < 8; ++k) n[k] = __builtin_nontemporal_load(&n4[lane + 64 * k]);

    float dp = 0.0f, dn = 0.0f;
    #pragma unroll
    for (int k = 0; k < 8; ++k) {
        float d;
        d = a[k].x - p[k].x; dp += d * d;
        d = a[k].y - p[k].y; dp += d * d;
        d = a[k].z - p[k].z; dp += d * d;
        d = a[k].w - p[k].w; dp += d * d;
        d = a[k].x - n[k].x; dn += d * d;
        d = a[k].y - n[k].y; dn += d * d;
        d = a[k].z - n[k].z; dn += d * d;
        d = a[k].w - n[k].w; dn += d * d;
    }

    // wave-64 butterfly reduce (two values, 12 wave-instructions total)
    #pragma unroll
    for (int off = 32; off > 0; off >>= 1) {
        dp += __shfl_down(dp, off);
        dn += __shfl_down(dn, off);
    }

    __shared__ float sl[RPB];
    if (lane == 0)
        sl[wave] = fmaxf(sqrtf(dp) - sqrtf(dn) + MARGIN, 0.0f);
    __syncthreads();

    if (tid == 0)
        ws[blockIdx.x] = (sl[0] + sl[1]) + (sl[2] + sl[3]);
}

// Stage 2: reduce NBLK (=4096) per-block partials -> out[0]. 16 KB read.
__global__ __launch_bounds__(256) void tl_reduce(
    const float* __restrict__ ws, float* __restrict__ out)
{
    const int tid  = threadIdx.x;
    const int lane = tid & 63;
    const int wave = tid >> 6;

    // 4096 floats = 1024 float4; 256 threads x 4 float4
    const vfloat4* w4 = (const vfloat4*)ws;
    float s = 0.0f;
    #pragma unroll
    for (int it = 0; it < 4; ++it) {
        const vfloat4 v = w4[it * 256 + tid];
        s += (v.x + v.y) + (v.z + v.w);
    }

    #pragma unroll
    for (int off = 32; off > 0; off >>= 1)
        s += __shfl_down(s, off);

    __shared__ float partial[4];
    if (lane == 0) partial[wave] = s;
    __syncthreads();

    if (tid == 0)
        out[0] = ((partial[0] + partial[1]) + (partial[2] + partial[3]))
                 * (1.0f / (float)B_ROWS);
}

extern "C" void kernel_launch(void* const* d_in, const int* in_sizes, int n_in,
                              void* d_out, int out_size, void* d_ws, size_t ws_size,
                              hipStream_t stream) {
    const float* anc = (const float*)d_in[0];
    const float* pos = (const float*)d_in[1];
    const float* neg = (const float*)d_in[2];
    float* out = (float*)d_out;
    float* ws  = (float*)d_ws;

    TripletLoss_90091234001212_kernel<<<NBLK, 256, 0, stream>>>(anc, pos, neg, ws);
    tl_reduce<<<1, 256, 0, stream>>>(ws, out);
}